// Round 1
// baseline (1878.268 us; speedup 1.0000x reference)
//
#include <hip/hip_runtime.h>

// ---------------------------------------------------------------------------
// TENProLayer on MI355X — round 0: full correct implementation.
// bf16 MFMA (16x16x32) GEMMs, fp32 residual/scan/softmax state.
// ---------------------------------------------------------------------------

typedef __bf16 bf16_t;
typedef bf16_t bf16x8 __attribute__((ext_vector_type(8)));
typedef bf16_t bf16x4 __attribute__((ext_vector_type(4)));
typedef float  f32x4  __attribute__((ext_vector_type(4)));

#define Tc   2048
#define Dc   1024
#define BTc  8192     // B*T
#define K2c  128      // 2K
#define MLPc 4096

// ---------------------------------------------------------------------------
// fp32 -> bf16 conversion (9 segments in one launch)
// ---------------------------------------------------------------------------
struct ConvSeg { const float* src; bf16_t* dst; int n; };
struct ConvArgs { ConvSeg s[9]; };

__global__ __launch_bounds__(256) void convert_kernel(ConvArgs a) {
    ConvSeg sg = a.s[blockIdx.y];
    int i = (blockIdx.x * 256 + threadIdx.x) * 4;
    if (i >= sg.n) return;
    float4 v = *(const float4*)(sg.src + i);
    bf16x4 o;
    o[0] = (bf16_t)v.x; o[1] = (bf16_t)v.y; o[2] = (bf16_t)v.z; o[3] = (bf16_t)v.w;
    *(bf16x4*)(sg.dst + i) = o;
}

// ---------------------------------------------------------------------------
// LayerNorm: fp32 in (row-major, D=1024) -> bf16 out. One block per row.
// ---------------------------------------------------------------------------
__global__ __launch_bounds__(256) void ln_kernel(const float* __restrict__ x,
                                                 const float* __restrict__ g,
                                                 const float* __restrict__ bb,
                                                 bf16_t* __restrict__ out) {
    int row = blockIdx.x;
    int tid = threadIdx.x;
    float4 v = ((const float4*)(x + (size_t)row * Dc))[tid];
    float s  = v.x + v.y + v.z + v.w;
    float ss = v.x * v.x + v.y * v.y + v.z * v.z + v.w * v.w;
#pragma unroll
    for (int d = 32; d > 0; d >>= 1) {
        s  += __shfl_down(s, d);
        ss += __shfl_down(ss, d);
    }
    __shared__ float red[8];
    int wv = tid >> 6;
    if ((tid & 63) == 0) { red[wv] = s; red[4 + wv] = ss; }
    __syncthreads();
    s  = red[0] + red[1] + red[2] + red[3];
    ss = red[4] + red[5] + red[6] + red[7];
    float mean = s * (1.0f / Dc);
    float var  = ss * (1.0f / Dc) - mean * mean;
    float rstd = rsqrtf(var + 1e-5f);
    float4 g4 = ((const float4*)g)[tid];
    float4 b4 = ((const float4*)bb)[tid];
    bf16x4 o;
    o[0] = (bf16_t)((v.x - mean) * rstd * g4.x + b4.x);
    o[1] = (bf16_t)((v.y - mean) * rstd * g4.y + b4.y);
    o[2] = (bf16_t)((v.z - mean) * rstd * g4.z + b4.z);
    o[3] = (bf16_t)((v.w - mean) * rstd * g4.w + b4.w);
    *(bf16x4*)(out + (size_t)row * Dc + tid * 4) = o;
}

// ---------------------------------------------------------------------------
// MFMA 32x32-per-wave inner loop: C[m,n] = sum_k A[m,k] * W[n,k]
// A,W row-major bf16; K multiple of 32.
// ---------------------------------------------------------------------------
__device__ __forceinline__ void mm32(const bf16_t* __restrict__ A,
                                     const bf16_t* __restrict__ W,
                                     int K, int m0, int n0,
                                     int lane16, int quad, f32x4 (&acc)[2][2]) {
    const bf16_t* a0 = A + (size_t)(m0 + lane16) * K + quad * 8;
    const bf16_t* a1 = a0 + (size_t)16 * K;
    const bf16_t* w0 = W + (size_t)(n0 + lane16) * K + quad * 8;
    const bf16_t* w1 = w0 + (size_t)16 * K;
#pragma unroll 4
    for (int k = 0; k < K; k += 32) {
        bf16x8 av0 = *(const bf16x8*)(a0 + k);
        bf16x8 av1 = *(const bf16x8*)(a1 + k);
        bf16x8 bv0 = *(const bf16x8*)(w0 + k);
        bf16x8 bv1 = *(const bf16x8*)(w1 + k);
        acc[0][0] = __builtin_amdgcn_mfma_f32_16x16x32_bf16(av0, bv0, acc[0][0], 0, 0, 0);
        acc[0][1] = __builtin_amdgcn_mfma_f32_16x16x32_bf16(av0, bv1, acc[0][1], 0, 0, 0);
        acc[1][0] = __builtin_amdgcn_mfma_f32_16x16x32_bf16(av1, bv0, acc[1][0], 0, 0, 0);
        acc[1][1] = __builtin_amdgcn_mfma_f32_16x16x32_bf16(av1, bv1, acc[1][1], 0, 0, 0);
    }
}

#define GEMM_PROLOG(NCOLS)                                        \
    int lane = threadIdx.x & 63;                                  \
    int wave = threadIdx.x >> 6;                                  \
    int gid  = blockIdx.x * 4 + wave;                             \
    int ntn  = (NCOLS) / 32;                                      \
    int mt = gid / ntn, nt = gid % ntn;                           \
    int m0 = mt * 32, n0 = nt * 32;                               \
    int lane16 = lane & 15, quad = lane >> 4;                     \
    f32x4 zz = {0.f, 0.f, 0.f, 0.f};                              \
    f32x4 acc[2][2] = {{zz, zz}, {zz, zz}};

#define GEMM_EPILOG_LOOP                                          \
    for (int mi = 0; mi < 2; mi++)                                \
        for (int ni = 0; ni < 2; ni++)                            \
            for (int r = 0; r < 4; r++)

#define ROWCOL                                                    \
    int row = m0 + mi * 16 + quad * 4 + r;                        \
    int col = n0 + ni * 16 + lane16;

// beta = x_norm @ in_proj^T + sigmoid(mg) * (prev @ mem_proj^T)
// written transposed into (B, 2K, T) for the scan.
__global__ __launch_bounds__(256) void gemm_beta(const bf16_t* __restrict__ xn,
                                                 const bf16_t* __restrict__ ipw,
                                                 const bf16_t* __restrict__ prevb,
                                                 const bf16_t* __restrict__ mpw,
                                                 const float* __restrict__ mgate_p,
                                                 float* __restrict__ beta_c) {
    GEMM_PROLOG(K2c)
    mm32(xn, ipw, Dc, m0, n0, lane16, quad, acc);
    f32x4 acc2[2][2] = {{zz, zz}, {zz, zz}};
    mm32(prevb, mpw, K2c, m0, n0, lane16, quad, acc2);
    float mg = 1.0f / (1.0f + __expf(-mgate_p[0]));
    GEMM_EPILOG_LOOP {
        ROWCOL
        int b = row >> 11, t = row & 2047;
        beta_c[((size_t)b * K2c + col) * Tc + t] = acc[mi][ni][r] + mg * acc2[mi][ni][r];
    }
}

// x1 = x + sigmoid(x_norm@mgw^T + mgb) * (eig@opw^T)
__global__ __launch_bounds__(256) void gemm_x1(const bf16_t* __restrict__ xn,
                                               const bf16_t* __restrict__ mgw,
                                               const bf16_t* __restrict__ eigb,
                                               const bf16_t* __restrict__ opw,
                                               const float* __restrict__ mgb,
                                               const float* __restrict__ x,
                                               float* __restrict__ xres) {
    GEMM_PROLOG(Dc)
    mm32(xn, mgw, Dc, m0, n0, lane16, quad, acc);
    f32x4 acch[2][2] = {{zz, zz}, {zz, zz}};
    mm32(eigb, opw, K2c, m0, n0, lane16, quad, acch);
    GEMM_EPILOG_LOOP {
        ROWCOL
        size_t o = (size_t)row * Dc + col;
        float gte = 1.0f / (1.0f + __expf(-(acc[mi][ni][r] + mgb[col])));
        xres[o] = x[o] + gte * acch[mi][ni][r];
    }
}

// qkv = attn_ln @ aiw^T + aib, scattered to (B,H,T,256) bf16
__global__ __launch_bounds__(256) void gemm_qkv(const bf16_t* __restrict__ a,
                                                const bf16_t* __restrict__ w,
                                                const float* __restrict__ bias,
                                                bf16_t* __restrict__ qb,
                                                bf16_t* __restrict__ kb,
                                                bf16_t* __restrict__ vb) {
    GEMM_PROLOG(3 * Dc)
    mm32(a, w, Dc, m0, n0, lane16, quad, acc);
    GEMM_EPILOG_LOOP {
        ROWCOL
        float v = acc[mi][ni][r] + bias[col];
        int part = col >> 10, d1 = col & 1023;
        int hh = d1 >> 8, hd = d1 & 255;
        int b = row >> 11, t = row & 2047;
        bf16_t* dst = (part == 0) ? qb : (part == 1) ? kb : vb;
        dst[(((size_t)(b * 4 + hh) * Tc + t) << 8) + hd] = (bf16_t)v;
    }
}

// x2 = x1 + ao @ aow^T + aob  (in place on xres)
__global__ __launch_bounds__(256) void gemm_attn_out(const bf16_t* __restrict__ a,
                                                     const bf16_t* __restrict__ w,
                                                     const float* __restrict__ bias,
                                                     float* __restrict__ xres) {
    GEMM_PROLOG(Dc)
    mm32(a, w, Dc, m0, n0, lane16, quad, acc);
    GEMM_EPILOG_LOOP {
        ROWCOL
        size_t o = (size_t)row * Dc + col;
        xres[o] = xres[o] + acc[mi][ni][r] + bias[col];
    }
}

// m = silu(x2_ln @ w1^T + b1) -> bf16
__global__ __launch_bounds__(256) void gemm_mlp1(const bf16_t* __restrict__ a,
                                                 const bf16_t* __restrict__ w,
                                                 const float* __restrict__ bias,
                                                 bf16_t* __restrict__ mbuf) {
    GEMM_PROLOG(MLPc)
    mm32(a, w, Dc, m0, n0, lane16, quad, acc);
    GEMM_EPILOG_LOOP {
        ROWCOL
        float v = acc[mi][ni][r] + bias[col];
        float sv = v / (1.0f + __expf(-v));
        mbuf[(size_t)row * MLPc + col] = (bf16_t)sv;
    }
}

// out = x2 + m @ w2^T + b2 (final output, fp32)
__global__ __launch_bounds__(256) void gemm_mlp2(const bf16_t* __restrict__ a,
                                                 const bf16_t* __restrict__ w,
                                                 const float* __restrict__ bias,
                                                 const float* __restrict__ xres,
                                                 float* __restrict__ outx) {
    GEMM_PROLOG(Dc)
    mm32(a, w, MLPc, m0, n0, lane16, quad, acc);
    GEMM_EPILOG_LOOP {
        ROWCOL
        size_t o = (size_t)row * Dc + col;
        outx[o] = xres[o] + acc[mi][ni][r] + bias[col];
    }
}

// ---------------------------------------------------------------------------
// Complex diagonal SSM scan: c_t = lam*c_{t-1} + beta_t over T=2048.
// One wave per (b,k) chain; 32 steps/lane; Kogge-Stone cross-lane scan with
// constant complex ratio lam^32 (5 squarings).
// beta_c/cbuf layout: (B, 2K, T): channel k = real, channel 64+k = imag.
// ---------------------------------------------------------------------------
__global__ __launch_bounds__(64) void scan_kernel(const float* __restrict__ beta_c,
                                                  const float* __restrict__ log_decay,
                                                  const float* __restrict__ freq,
                                                  float* __restrict__ cbuf) {
    int b = blockIdx.x >> 6;
    int k = blockIdx.x & 63;
    int lane = threadIdx.x;
    float lam = expf(log_decay[k]);
    float fr = freq[k];
    float lr = lam * cosf(fr), li = lam * sinf(fr);

    const float* br_p = beta_c + ((size_t)b * K2c + k) * Tc + lane * 32;
    const float* bi_p = beta_c + ((size_t)b * K2c + 64 + k) * Tc + lane * 32;
    float br[32], bi[32];
#pragma unroll
    for (int i = 0; i < 8; i++) {
        *(float4*)(&br[i * 4]) = ((const float4*)br_p)[i];
        *(float4*)(&bi[i * 4]) = ((const float4*)bi_p)[i];
    }
    float sr = 0.f, si = 0.f;
#pragma unroll
    for (int i = 0; i < 32; i++) {
        float nr = lr * sr - li * si + br[i];
        float ni = lr * si + li * sr + bi[i];
        sr = nr; si = ni;
    }
    // M = lam^32 (complex) via 5 squarings
    float Mr = lr, Mi = li;
#pragma unroll
    for (int i = 0; i < 5; i++) {
        float nr = Mr * Mr - Mi * Mi, ni = 2.f * Mr * Mi;
        Mr = nr; Mi = ni;
    }
    float ir = sr, ii = si;
#pragma unroll
    for (int d = 1; d < 64; d <<= 1) {
        float pr = __shfl_up(ir, d);
        float pi = __shfl_up(ii, d);
        if (lane >= d) {
            ir += Mr * pr - Mi * pi;
            ii += Mr * pi + Mi * pr;
        }
        float nr = Mr * Mr - Mi * Mi, ni = 2.f * Mr * Mi;
        Mr = nr; Mi = ni;
    }
    float cr = __shfl_up(ir, 1), ci = __shfl_up(ii, 1);
    if (lane == 0) { cr = 0.f; ci = 0.f; }
    float* cr_p = cbuf + ((size_t)b * K2c + k) * Tc + lane * 32;
    float* ci_p = cbuf + ((size_t)b * K2c + 64 + k) * Tc + lane * 32;
    sr = cr; si = ci;
#pragma unroll
    for (int i = 0; i < 32; i++) {
        float nr = lr * sr - li * si + br[i];
        float ni = lr * si + li * sr + bi[i];
        sr = nr; si = ni;
        cr_p[i] = sr; ci_p[i] = si;
    }
}

// ---------------------------------------------------------------------------
// Per-head coupling + concat: eig[b,t,ri*64+h*16+j] = sum_k cpl[h,j,k]*c[...]
// Writes output #2 (fp32) and a bf16 copy for the out_proj GEMM.
// ---------------------------------------------------------------------------
__global__ __launch_bounds__(256) void coupling_kernel(const float* __restrict__ cbuf,
                                                       const float* __restrict__ cpl,
                                                       float* __restrict__ eig_out,
                                                       bf16_t* __restrict__ eigb) {
    int idx = blockIdx.x * 256 + threadIdx.x;   // 1,048,576 total
    int col = idx & 127;
    int t = (idx >> 7) & 2047;
    int b = idx >> 18;
    int ri = col >> 6, hj = col & 63, h2 = hj >> 4, j = hj & 15;
    const float* crow = cbuf + ((size_t)b * K2c + ri * 64 + h2 * 16) * Tc + t;
    const float* cw = cpl + (h2 * 16 + j) * 16;
    float acc = 0.f;
#pragma unroll
    for (int kk = 0; kk < 16; kk++) acc += cw[kk] * crow[(size_t)kk * Tc];
    eig_out[idx] = acc;
    eigb[idx] = (bf16_t)acc;
}

// ---------------------------------------------------------------------------
// Sliding-window attention (WIN=128 -> 129 keys incl. self), HD=256, H=4.
// Block: 16 queries; key span 144 rows; K/V staged half-dim (128) at a time.
// Full (non-online) softmax: S tile is 16x144 fp32 in LDS. ~57 KB LDS.
// ---------------------------------------------------------------------------
#define TQ   16
#define NK   144
#define LDQ  264   // bf16 row stride for Q (256 + 8 pad), 16B-aligned rows
#define LDKV 136   // bf16 row stride for K/V half (128 + 8 pad)
#define LDS_S 161  // fp32 row stride for S

__global__ __launch_bounds__(256) void attn_kernel(const bf16_t* __restrict__ qb,
                                                   const bf16_t* __restrict__ kb,
                                                   const bf16_t* __restrict__ vb,
                                                   bf16_t* __restrict__ ao) {
    __shared__ bf16_t Qs[TQ * LDQ];
    __shared__ bf16_t KVs[NK * LDKV];
    __shared__ float  S[TQ * LDS_S];
    __shared__ float  l_l[TQ];

    int tid = threadIdx.x;
    int qt = blockIdx.x & 127;
    int bh = blockIdx.x >> 7;           // b*4 + h
    int q0 = qt * TQ;
    const bf16_t* qp = qb + (size_t)bh * Tc * 256;
    const bf16_t* kp = kb + (size_t)bh * Tc * 256;
    const bf16_t* vp = vb + (size_t)bh * Tc * 256;

    // load Q tile: 16 rows x 256 bf16 = 512 uint4
#pragma unroll
    for (int i = 0; i < 2; i++) {
        int lin = tid + i * 256;
        int row = lin >> 5, c = lin & 31;
        uint4 val = *(const uint4*)(qp + (size_t)(q0 + row) * 256 + c * 8);
        *(uint4*)(&Qs[row * LDQ + c * 8]) = val;
    }

    int q = tid >> 4;
    int kk0 = (tid & 15) * 9;     // 9 keys per thread (16*9 = 144)
    float s9[9];
#pragma unroll
    for (int j = 0; j < 9; j++) s9[j] = 0.f;

    // ---- S = Q K^T in two half-dim phases ----
    for (int ph = 0; ph < 2; ph++) {
        __syncthreads();
        // load K half: 144 rows x 128 bf16 = 2304 uint4
#pragma unroll
        for (int i = 0; i < 9; i++) {
            int lin = tid + i * 256;
            int row = lin >> 4, c = lin & 15;
            int kg = q0 - 128 + row;
            uint4 val = make_uint4(0u, 0u, 0u, 0u);
            if (kg >= 0) val = *(const uint4*)(kp + (size_t)kg * 256 + ph * 128 + c * 8);
            *(uint4*)(&KVs[row * LDKV + c * 8]) = val;
        }
        __syncthreads();
        for (int dt = 0; dt < 16; dt++) {
            float q8[8];
#pragma unroll
            for (int d = 0; d < 8; d++)
                q8[d] = (float)Qs[q * LDQ + ph * 128 + dt * 8 + d];
#pragma unroll
            for (int j = 0; j < 9; j++) {
                const bf16_t* kr = &KVs[(kk0 + j) * LDKV + dt * 8];
                float a = 0.f;
#pragma unroll
                for (int d = 0; d < 8; d++) a += q8[d] * (float)kr[d];
                s9[j] += a;
            }
        }
    }
    // mask + scale, write S
#pragma unroll
    for (int j = 0; j < 9; j++) {
        int kk = kk0 + j;
        int kg = q0 - 128 + kk;
        bool ok = (kg >= 0) && (kk >= q) && (kk <= q + 128);
        S[q * LDS_S + kk] = ok ? s9[j] * 0.0625f : -1e30f;
    }
    __syncthreads();
    // softmax over each row (one thread per query)
    if (tid < TQ) {
        float m = -1e30f;
        for (int kk = 0; kk < NK; kk++) m = fmaxf(m, S[tid * LDS_S + kk]);
        float l = 0.f;
        for (int kk = 0; kk < NK; kk++) {
            float p = __expf(S[tid * LDS_S + kk] - m);
            S[tid * LDS_S + kk] = p;
            l += p;
        }
        l_l[tid] = l;
    }

    // ---- O = P V in two half-dim phases ----
    int dq = tid & 15;
    int b = bh >> 2, h = bh & 3;
    for (int ph = 0; ph < 2; ph++) {
        __syncthreads();
#pragma unroll
        for (int i = 0; i < 9; i++) {
            int lin = tid + i * 256;
            int row = lin >> 4, c = lin & 15;
            int kg = q0 - 128 + row;
            uint4 val = make_uint4(0u, 0u, 0u, 0u);
            if (kg >= 0) val = *(const uint4*)(vp + (size_t)kg * 256 + ph * 128 + c * 8);
            *(uint4*)(&KVs[row * LDKV + c * 8]) = val;
        }
        __syncthreads();
        float o[8];
#pragma unroll
        for (int j = 0; j < 8; j++) o[j] = 0.f;
        int d0 = dq * 8;
        for (int kk = 0; kk < NK; kk++) {
            float p = S[q * LDS_S + kk];
            const bf16_t* vr = &KVs[kk * LDKV + d0];
#pragma unroll
            for (int j = 0; j < 8; j++) o[j] += p * (float)vr[j];
        }
        float rl = 1.0f / l_l[q];
        bf16_t* dst = ao + ((size_t)(b * Tc + q0 + q)) * Dc + h * 256 + ph * 128 + d0;
#pragma unroll
        for (int j = 0; j < 8; j++) dst[j] = (bf16_t)(o[j] * rl);
    }
}

// ---------------------------------------------------------------------------
// Launch
// ---------------------------------------------------------------------------
extern "C" void kernel_launch(void* const* d_in, const int* in_sizes, int n_in,
                              void* d_out, int out_size, void* d_ws, size_t ws_size,
                              hipStream_t stream) {
    const float* x            = (const float*)d_in[0];
    const float* prev_eig     = (const float*)d_in[1];
    const float* norm1_g      = (const float*)d_in[2];
    const float* norm1_b      = (const float*)d_in[3];
    const float* in_proj_w    = (const float*)d_in[4];
    const float* memory_gate  = (const float*)d_in[5];
    const float* memory_proj_w= (const float*)d_in[6];
    const float* log_decay    = (const float*)d_in[7];
    const float* frequency    = (const float*)d_in[8];
    const float* coupling     = (const float*)d_in[9];
    const float* main_gate_w  = (const float*)d_in[10];
    const float* main_gate_b  = (const float*)d_in[11];
    const float* out_proj_w   = (const float*)d_in[12];
    const float* attn_norm_g  = (const float*)d_in[13];
    const float* attn_norm_b  = (const float*)d_in[14];
    const float* attn_in_w    = (const float*)d_in[15];
    const float* attn_in_b    = (const float*)d_in[16];
    const float* attn_out_w   = (const float*)d_in[17];
    const float* attn_out_b   = (const float*)d_in[18];
    const float* norm2_g      = (const float*)d_in[19];
    const float* norm2_b      = (const float*)d_in[20];
    const float* mlp_w1       = (const float*)d_in[21];
    const float* mlp_b1       = (const float*)d_in[22];
    const float* mlp_w2       = (const float*)d_in[23];
    const float* mlp_b2       = (const float*)d_in[24];

    char* ws = (char*)d_ws;
    // bf16 weight region
    bf16_t* ipw_b  = (bf16_t*)(ws + 0);          // 128x1024   (262144 B)
    bf16_t* mpw_b  = (bf16_t*)(ws + 262144);     // 128x128    (32768 B)
    bf16_t* mgw_b  = (bf16_t*)(ws + 294912);     // 1024x1024  (2097152 B)
    bf16_t* opw_b  = (bf16_t*)(ws + 2392064);    // 1024x128   (262144 B)
    bf16_t* aiw_b  = (bf16_t*)(ws + 2654208);    // 3072x1024  (6291456 B)
    bf16_t* aow_b  = (bf16_t*)(ws + 8945664);    // 1024x1024  (2097152 B)
    bf16_t* w1_b   = (bf16_t*)(ws + 11042816);   // 4096x1024  (8388608 B)
    bf16_t* w2_b   = (bf16_t*)(ws + 19431424);   // 1024x4096  (8388608 B)
    bf16_t* prev_b = (bf16_t*)(ws + 27820032);   // 8192x128   (2097152 B)
    const size_t OFF_ACTA = 29917184;            // 16 MB: bf16 activation (reused)
    const size_t OFF_BIG  = OFF_ACTA + 16777216; // 64 MB region (time-multiplexed)
    bf16_t* actA   = (bf16_t*)(ws + OFF_ACTA);
    float*  beta_c = (float*)(ws + OFF_BIG);                   // (B,2K,T) 4 MB
    float*  cbuf   = (float*)(ws + OFF_BIG + 4194304);         // (B,2K,T) 4 MB
    bf16_t* eigb   = (bf16_t*)(ws + OFF_BIG + 8388608);        // (BT,128) 2 MB
    bf16_t* qbuf   = (bf16_t*)(ws + OFF_BIG);                  // 16 MB
    bf16_t* kbuf   = (bf16_t*)(ws + OFF_BIG + 16777216);       // 16 MB
    bf16_t* vbuf   = (bf16_t*)(ws + OFF_BIG + 33554432);       // 16 MB
    bf16_t* mbuf   = (bf16_t*)(ws + OFF_BIG);                  // 64 MB

    float* out_x   = (float*)d_out;              // (B,T,D) fp32 — also residual scratch
    float* out_eig = out_x + (size_t)BTc * Dc;   // (B,T,2K) fp32
    float* xres    = out_x;

    // 1) weight/prev fp32 -> bf16
    ConvArgs ca;
    ca.s[0] = ConvSeg{in_proj_w,     ipw_b,  131072};
    ca.s[1] = ConvSeg{memory_proj_w, mpw_b,  16384};
    ca.s[2] = ConvSeg{main_gate_w,   mgw_b,  1048576};
    ca.s[3] = ConvSeg{out_proj_w,    opw_b,  131072};
    ca.s[4] = ConvSeg{attn_in_w,     aiw_b,  3145728};
    ca.s[5] = ConvSeg{attn_out_w,    aow_b,  1048576};
    ca.s[6] = ConvSeg{mlp_w1,        w1_b,   4194304};
    ca.s[7] = ConvSeg{mlp_w2,        w2_b,   4194304};
    ca.s[8] = ConvSeg{prev_eig,      prev_b, 1048576};
    convert_kernel<<<dim3(4096, 9), 256, 0, stream>>>(ca);

    // 2) LN1 -> x_norm (bf16)
    ln_kernel<<<BTc, 256, 0, stream>>>(x, norm1_g, norm1_b, actA);
    // 3) beta (with memory gate), transposed (B,2K,T)
    gemm_beta<<<256, 256, 0, stream>>>(actA, ipw_b, prev_b, mpw_b, memory_gate, beta_c);
    // 4) complex SSM scan
    scan_kernel<<<256, 64, 0, stream>>>(beta_c, log_decay, frequency, cbuf);
    // 5) per-head coupling -> eigenstates (output #2) + bf16 copy
    coupling_kernel<<<4096, 256, 0, stream>>>(cbuf, coupling, out_eig, eigb);
    // 6) x1 = x + sigmoid(gate)*(eig@opw^T)
    gemm_x1<<<2048, 256, 0, stream>>>(actA, mgw_b, eigb, opw_b, main_gate_b, x, xres);
    // 7) attn LN
    ln_kernel<<<BTc, 256, 0, stream>>>(xres, attn_norm_g, attn_norm_b, actA);
    // 8) qkv
    gemm_qkv<<<6144, 256, 0, stream>>>(actA, aiw_b, attn_in_b, qbuf, kbuf, vbuf);
    // 9) sliding-window attention -> ao (bf16, reuses actA)
    attn_kernel<<<2048, 256, 0, stream>>>(qbuf, kbuf, vbuf, actA);
    // 10) x2 = x1 + ao@aow^T + b (in place)
    gemm_attn_out<<<2048, 256, 0, stream>>>(actA, aow_b, attn_out_b, xres);
    // 11) LN2
    ln_kernel<<<BTc, 256, 0, stream>>>(xres, norm2_g, norm2_b, actA);
    // 12) mlp1 (silu)
    gemm_mlp1<<<8192, 256, 0, stream>>>(actA, w1_b, mlp_b1, mbuf);
    // 13) mlp2 + residual -> final x (output #1)
    gemm_mlp2<<<2048, 256, 0, stream>>>(mbuf, w2_b, mlp_b2, xres, out_x);

    (void)in_sizes; (void)n_in; (void)out_size; (void)ws_size;
}

// Round 2
// 799.533 us; speedup vs baseline: 2.3492x; 2.3492x over previous
//
#include <hip/hip_runtime.h>

// ---------------------------------------------------------------------------
// TENProLayer on MI355X — round 1: m97-style LDS-tiled MFMA GEMMs
// (128x128 tile, BK=32, global_load_lds width-16, 2-barrier K-loop).
// ---------------------------------------------------------------------------

typedef __bf16 bf16_t;
typedef bf16_t bf16x8 __attribute__((ext_vector_type(8)));
typedef bf16_t bf16x4 __attribute__((ext_vector_type(4)));
typedef float  f32x4  __attribute__((ext_vector_type(4)));

#define Tc   2048
#define Dc   1024
#define BTc  8192     // B*T
#define K2c  128      // 2K
#define MLPc 4096

// ---------------------------------------------------------------------------
// fp32 -> bf16 conversion (9 segments in one launch)
// ---------------------------------------------------------------------------
struct ConvSeg { const float* src; bf16_t* dst; int n; };
struct ConvArgs { ConvSeg s[9]; };

__global__ __launch_bounds__(256) void convert_kernel(ConvArgs a) {
    ConvSeg sg = a.s[blockIdx.y];
    int i = (blockIdx.x * 256 + threadIdx.x) * 4;
    if (i >= sg.n) return;
    float4 v = *(const float4*)(sg.src + i);
    bf16x4 o;
    o[0] = (bf16_t)v.x; o[1] = (bf16_t)v.y; o[2] = (bf16_t)v.z; o[3] = (bf16_t)v.w;
    *(bf16x4*)(sg.dst + i) = o;
}

// ---------------------------------------------------------------------------
// LayerNorm: fp32 in (row-major, D=1024) -> bf16 out. One block per row.
// ---------------------------------------------------------------------------
__global__ __launch_bounds__(256) void ln_kernel(const float* __restrict__ x,
                                                 const float* __restrict__ g,
                                                 const float* __restrict__ bb,
                                                 bf16_t* __restrict__ out) {
    int row = blockIdx.x;
    int tid = threadIdx.x;
    float4 v = ((const float4*)(x + (size_t)row * Dc))[tid];
    float s  = v.x + v.y + v.z + v.w;
    float ss = v.x * v.x + v.y * v.y + v.z * v.z + v.w * v.w;
#pragma unroll
    for (int d = 32; d > 0; d >>= 1) {
        s  += __shfl_down(s, d);
        ss += __shfl_down(ss, d);
    }
    __shared__ float red[8];
    int wv = tid >> 6;
    if ((tid & 63) == 0) { red[wv] = s; red[4 + wv] = ss; }
    __syncthreads();
    s  = red[0] + red[1] + red[2] + red[3];
    ss = red[4] + red[5] + red[6] + red[7];
    float mean = s * (1.0f / Dc);
    float var  = ss * (1.0f / Dc) - mean * mean;
    float rstd = rsqrtf(var + 1e-5f);
    float4 g4 = ((const float4*)g)[tid];
    float4 b4 = ((const float4*)bb)[tid];
    bf16x4 o;
    o[0] = (bf16_t)((v.x - mean) * rstd * g4.x + b4.x);
    o[1] = (bf16_t)((v.y - mean) * rstd * g4.y + b4.y);
    o[2] = (bf16_t)((v.z - mean) * rstd * g4.z + b4.z);
    o[3] = (bf16_t)((v.w - mean) * rstd * g4.w + b4.w);
    *(bf16x4*)(out + (size_t)row * Dc + tid * 4) = o;
}

// ---------------------------------------------------------------------------
// m97-style tiled GEMM: C[m,n] = sum_k A[m,k]*W[n,k], A: MxK, W: NxK (bf16,
// row-major). 128x128 tile, BK=32, 4 waves, each wave 64x64 (4x4 MFMA accs).
// global_load_lds width-16 staging (wave-uniform LDS base + lane*16 layout).
// ---------------------------------------------------------------------------
#define BM 128
#define BN 128
#define BK 32

struct EpiParams {
    const float* bias;
    float*       fout;
    const float* fin;
    bf16_t*      bout;
    bf16_t*      q; bf16_t* k; bf16_t* v;
    const float* hbuf;
};

#define GLOAD_LDS(g, l)                                                        \
    __builtin_amdgcn_global_load_lds(                                          \
        (const __attribute__((address_space(1))) unsigned int*)(g),            \
        (__attribute__((address_space(3))) unsigned int*)(l), 16, 0, 0)

template <int EPI>
__global__ __launch_bounds__(256) void gemm_tiled(const bf16_t* __restrict__ A,
                                                  const bf16_t* __restrict__ W,
                                                  int M, int N, int K,
                                                  EpiParams ep) {
    __shared__ bf16_t As[BM * BK];
    __shared__ bf16_t Bs[BN * BK];

    int tid = threadIdx.x;
    int wv = tid >> 6, lane = tid & 63;
    int lane16 = lane & 15, quad = lane >> 4;
    int nbn = N / BN;
    int bm = blockIdx.x / nbn, bn = blockIdx.x % nbn;
    int m0 = bm * BM, n0 = bn * BN;
    int wm = (wv >> 1) * 64, wn = (wv & 1) * 64;

    // staging addresses: wave wv covers rows [wv*16, wv*16+16) (+64 for issue 1)
    int lrow = lane >> 2;           // 0..15
    int lcol = (lane & 3) * 8;      // element col within BK
    const bf16_t* ga = A + (size_t)(m0 + wv * 16 + lrow) * K + lcol;
    const bf16_t* gb = W + (size_t)(n0 + wv * 16 + lrow) * K + lcol;
    size_t gstep64 = (size_t)64 * K;
    bf16_t* la0 = &As[(wv * 16) * BK];
    bf16_t* la1 = &As[(64 + wv * 16) * BK];
    bf16_t* lb0 = &Bs[(wv * 16) * BK];
    bf16_t* lb1 = &Bs[(64 + wv * 16) * BK];

    f32x4 zz = {0.f, 0.f, 0.f, 0.f};
    f32x4 acc[4][4];
#pragma unroll
    for (int mi = 0; mi < 4; mi++)
#pragma unroll
        for (int ni = 0; ni < 4; ni++) acc[mi][ni] = zz;

    for (int k0 = 0; k0 < K; k0 += BK) {
        GLOAD_LDS(ga + k0, la0);
        GLOAD_LDS(ga + k0 + gstep64, la1);
        GLOAD_LDS(gb + k0, lb0);
        GLOAD_LDS(gb + k0 + gstep64, lb1);
        __syncthreads();   // waits vmcnt(0): LDS tiles filled
        bf16x8 af[4], bf[4];
#pragma unroll
        for (int mi = 0; mi < 4; mi++)
            af[mi] = *(const bf16x8*)&As[(wm + mi * 16 + lane16) * BK + quad * 8];
#pragma unroll
        for (int ni = 0; ni < 4; ni++)
            bf[ni] = *(const bf16x8*)&Bs[(wn + ni * 16 + lane16) * BK + quad * 8];
#pragma unroll
        for (int mi = 0; mi < 4; mi++)
#pragma unroll
            for (int ni = 0; ni < 4; ni++)
                acc[mi][ni] = __builtin_amdgcn_mfma_f32_16x16x32_bf16(
                    af[mi], bf[ni], acc[mi][ni], 0, 0, 0);
        __syncthreads();   // all waves done reading before next overwrite
    }

#pragma unroll
    for (int mi = 0; mi < 4; mi++)
#pragma unroll
        for (int ni = 0; ni < 4; ni++)
#pragma unroll
            for (int r = 0; r < 4; r++) {
                int row = m0 + wm + mi * 16 + quad * 4 + r;
                int col = n0 + wn + ni * 16 + lane16;
                float v = acc[mi][ni][r];
                if constexpr (EPI == 0) {          // plain fp32 store
                    ep.fout[(size_t)row * N + col] = v;
                } else if constexpr (EPI == 1) {   // mlp1: silu -> bf16
                    v += ep.bias[col];
                    ep.bout[(size_t)row * N + col] = (bf16_t)(v / (1.0f + __expf(-v)));
                } else if constexpr (EPI == 2) {   // residual + bias -> fp32
                    size_t o = (size_t)row * N + col;
                    ep.fout[o] = ep.fin[o] + v + ep.bias[col];
                } else if constexpr (EPI == 3) {   // qkv: bias + scatter bf16
                    v += ep.bias[col];
                    int part = col >> 10, d1 = col & 1023;
                    int hh = d1 >> 8, hd = d1 & 255;
                    int b = row >> 11, t = row & 2047;
                    bf16_t* dst = (part == 0) ? ep.q : (part == 1) ? ep.k : ep.v;
                    dst[(((size_t)(b * 4 + hh) * Tc + t) << 8) + hd] = (bf16_t)v;
                } else if constexpr (EPI == 4) {   // spectral gate
                    size_t o = (size_t)row * N + col;
                    float g = 1.0f / (1.0f + __expf(-(v + ep.bias[col])));
                    ep.fout[o] = ep.fin[o] + g * ep.hbuf[o];
                }
            }
}

// ---------------------------------------------------------------------------
// Small-N GEMM (beta, N=128): 32x32-per-wave direct-load MFMA (round-0 path).
// ---------------------------------------------------------------------------
__device__ __forceinline__ void mm32(const bf16_t* __restrict__ A,
                                     const bf16_t* __restrict__ W,
                                     int K, int m0, int n0,
                                     int lane16, int quad, f32x4 (&acc)[2][2]) {
    const bf16_t* a0 = A + (size_t)(m0 + lane16) * K + quad * 8;
    const bf16_t* a1 = a0 + (size_t)16 * K;
    const bf16_t* w0 = W + (size_t)(n0 + lane16) * K + quad * 8;
    const bf16_t* w1 = w0 + (size_t)16 * K;
#pragma unroll 4
    for (int k = 0; k < K; k += 32) {
        bf16x8 av0 = *(const bf16x8*)(a0 + k);
        bf16x8 av1 = *(const bf16x8*)(a1 + k);
        bf16x8 bv0 = *(const bf16x8*)(w0 + k);
        bf16x8 bv1 = *(const bf16x8*)(w1 + k);
        acc[0][0] = __builtin_amdgcn_mfma_f32_16x16x32_bf16(av0, bv0, acc[0][0], 0, 0, 0);
        acc[0][1] = __builtin_amdgcn_mfma_f32_16x16x32_bf16(av0, bv1, acc[0][1], 0, 0, 0);
        acc[1][0] = __builtin_amdgcn_mfma_f32_16x16x32_bf16(av1, bv0, acc[1][0], 0, 0, 0);
        acc[1][1] = __builtin_amdgcn_mfma_f32_16x16x32_bf16(av1, bv1, acc[1][1], 0, 0, 0);
    }
}

// beta = x_norm @ in_proj^T + sigmoid(mg)*(prev @ mem_proj^T), transposed (B,2K,T)
__global__ __launch_bounds__(256) void gemm_beta(const bf16_t* __restrict__ xn,
                                                 const bf16_t* __restrict__ ipw,
                                                 const bf16_t* __restrict__ prevb,
                                                 const bf16_t* __restrict__ mpw,
                                                 const float* __restrict__ mgate_p,
                                                 float* __restrict__ beta_c) {
    int lane = threadIdx.x & 63;
    int wave = threadIdx.x >> 6;
    int gid  = blockIdx.x * 4 + wave;
    int mt = gid / 4, nt = gid % 4;
    int m0 = mt * 32, n0 = nt * 32;
    int lane16 = lane & 15, quad = lane >> 4;
    f32x4 zz = {0.f, 0.f, 0.f, 0.f};
    f32x4 acc[2][2] = {{zz, zz}, {zz, zz}};
    mm32(xn, ipw, Dc, m0, n0, lane16, quad, acc);
    f32x4 acc2[2][2] = {{zz, zz}, {zz, zz}};
    mm32(prevb, mpw, K2c, m0, n0, lane16, quad, acc2);
    float mg = 1.0f / (1.0f + __expf(-mgate_p[0]));
    for (int mi = 0; mi < 2; mi++)
        for (int ni = 0; ni < 2; ni++)
            for (int r = 0; r < 4; r++) {
                int row = m0 + mi * 16 + quad * 4 + r;
                int col = n0 + ni * 16 + lane16;
                int b = row >> 11, t = row & 2047;
                beta_c[((size_t)b * K2c + col) * Tc + t] =
                    acc[mi][ni][r] + mg * acc2[mi][ni][r];
            }
}

// ---------------------------------------------------------------------------
// Complex diagonal SSM scan (wave-parallel Kogge-Stone, 32 steps/lane).
// ---------------------------------------------------------------------------
__global__ __launch_bounds__(64) void scan_kernel(const float* __restrict__ beta_c,
                                                  const float* __restrict__ log_decay,
                                                  const float* __restrict__ freq,
                                                  float* __restrict__ cbuf) {
    int b = blockIdx.x >> 6;
    int k = blockIdx.x & 63;
    int lane = threadIdx.x;
    float lam = expf(log_decay[k]);
    float fr = freq[k];
    float lr = lam * cosf(fr), li = lam * sinf(fr);

    const float* br_p = beta_c + ((size_t)b * K2c + k) * Tc + lane * 32;
    const float* bi_p = beta_c + ((size_t)b * K2c + 64 + k) * Tc + lane * 32;
    float br[32], bi[32];
#pragma unroll
    for (int i = 0; i < 8; i++) {
        *(float4*)(&br[i * 4]) = ((const float4*)br_p)[i];
        *(float4*)(&bi[i * 4]) = ((const float4*)bi_p)[i];
    }
    float sr = 0.f, si = 0.f;
#pragma unroll
    for (int i = 0; i < 32; i++) {
        float nr = lr * sr - li * si + br[i];
        float ni = lr * si + li * sr + bi[i];
        sr = nr; si = ni;
    }
    float Mr = lr, Mi = li;
#pragma unroll
    for (int i = 0; i < 5; i++) {
        float nr = Mr * Mr - Mi * Mi, ni = 2.f * Mr * Mi;
        Mr = nr; Mi = ni;
    }
    float ir = sr, ii = si;
#pragma unroll
    for (int d = 1; d < 64; d <<= 1) {
        float pr = __shfl_up(ir, d);
        float pi = __shfl_up(ii, d);
        if (lane >= d) {
            ir += Mr * pr - Mi * pi;
            ii += Mr * pi + Mi * pr;
        }
        float nr = Mr * Mr - Mi * Mi, ni = 2.f * Mr * Mi;
        Mr = nr; Mi = ni;
    }
    float cr = __shfl_up(ir, 1), ci = __shfl_up(ii, 1);
    if (lane == 0) { cr = 0.f; ci = 0.f; }
    float* cr_p = cbuf + ((size_t)b * K2c + k) * Tc + lane * 32;
    float* ci_p = cbuf + ((size_t)b * K2c + 64 + k) * Tc + lane * 32;
    sr = cr; si = ci;
#pragma unroll
    for (int i = 0; i < 32; i++) {
        float nr = lr * sr - li * si + br[i];
        float ni = lr * si + li * sr + bi[i];
        sr = nr; si = ni;
        cr_p[i] = sr; ci_p[i] = si;
    }
}

// ---------------------------------------------------------------------------
// Per-head coupling + concat -> eigenstates (fp32 output #2 + bf16 copy)
// ---------------------------------------------------------------------------
__global__ __launch_bounds__(256) void coupling_kernel(const float* __restrict__ cbuf,
                                                       const float* __restrict__ cpl,
                                                       float* __restrict__ eig_out,
                                                       bf16_t* __restrict__ eigb) {
    int idx = blockIdx.x * 256 + threadIdx.x;
    int col = idx & 127;
    int t = (idx >> 7) & 2047;
    int b = idx >> 18;
    int ri = col >> 6, hj = col & 63, h2 = hj >> 4, j = hj & 15;
    const float* crow = cbuf + ((size_t)b * K2c + ri * 64 + h2 * 16) * Tc + t;
    const float* cw = cpl + (h2 * 16 + j) * 16;
    float acc = 0.f;
#pragma unroll
    for (int kk = 0; kk < 16; kk++) acc += cw[kk] * crow[(size_t)kk * Tc];
    eig_out[idx] = acc;
    eigb[idx] = (bf16_t)acc;
}

// ---------------------------------------------------------------------------
// Sliding-window attention (WIN=128), HD=256, 16 queries/block, 144-key span.
// ---------------------------------------------------------------------------
#define TQ   16
#define NK   144
#define LDQ  264
#define LDKV 136
#define LDS_S 161

__global__ __launch_bounds__(256) void attn_kernel(const bf16_t* __restrict__ qb,
                                                   const bf16_t* __restrict__ kb,
                                                   const bf16_t* __restrict__ vb,
                                                   bf16_t* __restrict__ ao) {
    __shared__ bf16_t Qs[TQ * LDQ];
    __shared__ bf16_t KVs[NK * LDKV];
    __shared__ float  S[TQ * LDS_S];
    __shared__ float  l_l[TQ];

    int tid = threadIdx.x;
    int qt = blockIdx.x & 127;
    int bh = blockIdx.x >> 7;
    int q0 = qt * TQ;
    const bf16_t* qp = qb + (size_t)bh * Tc * 256;
    const bf16_t* kp = kb + (size_t)bh * Tc * 256;
    const bf16_t* vp = vb + (size_t)bh * Tc * 256;

#pragma unroll
    for (int i = 0; i < 2; i++) {
        int lin = tid + i * 256;
        int row = lin >> 5, c = lin & 31;
        uint4 val = *(const uint4*)(qp + (size_t)(q0 + row) * 256 + c * 8);
        *(uint4*)(&Qs[row * LDQ + c * 8]) = val;
    }

    int q = tid >> 4;
    int kk0 = (tid & 15) * 9;
    float s9[9];
#pragma unroll
    for (int j = 0; j < 9; j++) s9[j] = 0.f;

    for (int ph = 0; ph < 2; ph++) {
        __syncthreads();
#pragma unroll
        for (int i = 0; i < 9; i++) {
            int lin = tid + i * 256;
            int row = lin >> 4, c = lin & 15;
            int kg = q0 - 128 + row;
            uint4 val = make_uint4(0u, 0u, 0u, 0u);
            if (kg >= 0) val = *(const uint4*)(kp + (size_t)kg * 256 + ph * 128 + c * 8);
            *(uint4*)(&KVs[row * LDKV + c * 8]) = val;
        }
        __syncthreads();
        for (int dt = 0; dt < 16; dt++) {
            float q8[8];
#pragma unroll
            for (int d = 0; d < 8; d++)
                q8[d] = (float)Qs[q * LDQ + ph * 128 + dt * 8 + d];
#pragma unroll
            for (int j = 0; j < 9; j++) {
                const bf16_t* kr = &KVs[(kk0 + j) * LDKV + dt * 8];
                float a = 0.f;
#pragma unroll
                for (int d = 0; d < 8; d++) a += q8[d] * (float)kr[d];
                s9[j] += a;
            }
        }
    }
#pragma unroll
    for (int j = 0; j < 9; j++) {
        int kk = kk0 + j;
        int kg = q0 - 128 + kk;
        bool ok = (kg >= 0) && (kk >= q) && (kk <= q + 128);
        S[q * LDS_S + kk] = ok ? s9[j] * 0.0625f : -1e30f;
    }
    __syncthreads();
    if (tid < TQ) {
        float m = -1e30f;
        for (int kk = 0; kk < NK; kk++) m = fmaxf(m, S[tid * LDS_S + kk]);
        float l = 0.f;
        for (int kk = 0; kk < NK; kk++) {
            float p = __expf(S[tid * LDS_S + kk] - m);
            S[tid * LDS_S + kk] = p;
            l += p;
        }
        l_l[tid] = l;
    }

    int dq = tid & 15;
    int b = bh >> 2, h = bh & 3;
    for (int ph = 0; ph < 2; ph++) {
        __syncthreads();
#pragma unroll
        for (int i = 0; i < 9; i++) {
            int lin = tid + i * 256;
            int row = lin >> 4, c = lin & 15;
            int kg = q0 - 128 + row;
            uint4 val = make_uint4(0u, 0u, 0u, 0u);
            if (kg >= 0) val = *(const uint4*)(vp + (size_t)kg * 256 + ph * 128 + c * 8);
            *(uint4*)(&KVs[row * LDKV + c * 8]) = val;
        }
        __syncthreads();
        float o[8];
#pragma unroll
        for (int j = 0; j < 8; j++) o[j] = 0.f;
        int d0 = dq * 8;
        for (int kk = 0; kk < NK; kk++) {
            float p = S[q * LDS_S + kk];
            const bf16_t* vr = &KVs[kk * LDKV + d0];
#pragma unroll
            for (int j = 0; j < 8; j++) o[j] += p * (float)vr[j];
        }
        float rl = 1.0f / l_l[q];
        bf16_t* dst = ao + ((size_t)(b * Tc + q0 + q)) * Dc + h * 256 + ph * 128 + d0;
#pragma unroll
        for (int j = 0; j < 8; j++) dst[j] = (bf16_t)(o[j] * rl);
    }
}

// ---------------------------------------------------------------------------
// Launch
// ---------------------------------------------------------------------------
extern "C" void kernel_launch(void* const* d_in, const int* in_sizes, int n_in,
                              void* d_out, int out_size, void* d_ws, size_t ws_size,
                              hipStream_t stream) {
    const float* x            = (const float*)d_in[0];
    const float* prev_eig     = (const float*)d_in[1];
    const float* norm1_g      = (const float*)d_in[2];
    const float* norm1_b      = (const float*)d_in[3];
    const float* in_proj_w    = (const float*)d_in[4];
    const float* memory_gate  = (const float*)d_in[5];
    const float* memory_proj_w= (const float*)d_in[6];
    const float* log_decay    = (const float*)d_in[7];
    const float* frequency    = (const float*)d_in[8];
    const float* coupling     = (const float*)d_in[9];
    const float* main_gate_w  = (const float*)d_in[10];
    const float* main_gate_b  = (const float*)d_in[11];
    const float* out_proj_w   = (const float*)d_in[12];
    const float* attn_norm_g  = (const float*)d_in[13];
    const float* attn_norm_b  = (const float*)d_in[14];
    const float* attn_in_w    = (const float*)d_in[15];
    const float* attn_in_b    = (const float*)d_in[16];
    const float* attn_out_w   = (const float*)d_in[17];
    const float* attn_out_b   = (const float*)d_in[18];
    const float* norm2_g      = (const float*)d_in[19];
    const float* norm2_b      = (const float*)d_in[20];
    const float* mlp_w1       = (const float*)d_in[21];
    const float* mlp_b1       = (const float*)d_in[22];
    const float* mlp_w2       = (const float*)d_in[23];
    const float* mlp_b2       = (const float*)d_in[24];

    char* ws = (char*)d_ws;
    bf16_t* ipw_b  = (bf16_t*)(ws + 0);
    bf16_t* mpw_b  = (bf16_t*)(ws + 262144);
    bf16_t* mgw_b  = (bf16_t*)(ws + 294912);
    bf16_t* opw_b  = (bf16_t*)(ws + 2392064);
    bf16_t* aiw_b  = (bf16_t*)(ws + 2654208);
    bf16_t* aow_b  = (bf16_t*)(ws + 8945664);
    bf16_t* w1_b   = (bf16_t*)(ws + 11042816);
    bf16_t* w2_b   = (bf16_t*)(ws + 19431424);
    bf16_t* prev_b = (bf16_t*)(ws + 27820032);
    const size_t OFF_ACTA = 29917184;
    const size_t OFF_BIG  = OFF_ACTA + 16777216;
    bf16_t* actA   = (bf16_t*)(ws + OFF_ACTA);
    float*  beta_c = (float*)(ws + OFF_BIG);                   // 4 MB
    float*  cbuf   = (float*)(ws + OFF_BIG + 4194304);         // 4 MB
    bf16_t* eigb   = (bf16_t*)(ws + OFF_BIG + 8388608);        // 2 MB
    float*  hbuf   = (float*)(ws + OFF_BIG + 16777216);        // 32 MB (dead before kbuf)
    bf16_t* qbuf   = (bf16_t*)(ws + OFF_BIG);                  // 16 MB
    bf16_t* kbuf   = (bf16_t*)(ws + OFF_BIG + 16777216);       // 16 MB
    bf16_t* vbuf   = (bf16_t*)(ws + OFF_BIG + 33554432);       // 16 MB
    bf16_t* mbuf   = (bf16_t*)(ws + OFF_BIG);                  // 64 MB

    float* out_x   = (float*)d_out;
    float* out_eig = out_x + (size_t)BTc * Dc;
    float* xres    = out_x;

    ConvArgs ca;
    ca.s[0] = ConvSeg{in_proj_w,     ipw_b,  131072};
    ca.s[1] = ConvSeg{memory_proj_w, mpw_b,  16384};
    ca.s[2] = ConvSeg{main_gate_w,   mgw_b,  1048576};
    ca.s[3] = ConvSeg{out_proj_w,    opw_b,  131072};
    ca.s[4] = ConvSeg{attn_in_w,     aiw_b,  3145728};
    ca.s[5] = ConvSeg{attn_out_w,    aow_b,  1048576};
    ca.s[6] = ConvSeg{mlp_w1,        w1_b,   4194304};
    ca.s[7] = ConvSeg{mlp_w2,        w2_b,   4194304};
    ca.s[8] = ConvSeg{prev_eig,      prev_b, 1048576};
    convert_kernel<<<dim3(4096, 9), 256, 0, stream>>>(ca);

    EpiParams ep{};

    // LN1 -> x_norm (bf16)
    ln_kernel<<<BTc, 256, 0, stream>>>(x, norm1_g, norm1_b, actA);
    // beta (transposed (B,2K,T))
    gemm_beta<<<256, 256, 0, stream>>>(actA, ipw_b, prev_b, mpw_b, memory_gate, beta_c);
    // SSM scan
    scan_kernel<<<256, 64, 0, stream>>>(beta_c, log_decay, frequency, cbuf);
    // coupling -> eigenstates (output #2) + bf16 copy
    coupling_kernel<<<4096, 256, 0, stream>>>(cbuf, coupling, out_eig, eigb);
    // h = eig @ opw^T  (fp32 scratch)
    ep = EpiParams{}; ep.fout = hbuf;
    gemm_tiled<0><<<(BTc/BM)*(Dc/BN), 256, 0, stream>>>(eigb, opw_b, BTc, Dc, K2c, ep);
    // x1 = x + sigmoid(xn@mgw^T + mgb) * h
    ep = EpiParams{}; ep.bias = main_gate_b; ep.fin = x; ep.fout = xres; ep.hbuf = hbuf;
    gemm_tiled<4><<<(BTc/BM)*(Dc/BN), 256, 0, stream>>>(actA, mgw_b, BTc, Dc, Dc, ep);
    // attn LN
    ln_kernel<<<BTc, 256, 0, stream>>>(xres, attn_norm_g, attn_norm_b, actA);
    // qkv
    ep = EpiParams{}; ep.bias = attn_in_b; ep.q = qbuf; ep.k = kbuf; ep.v = vbuf;
    gemm_tiled<3><<<(BTc/BM)*(3*Dc/BN), 256, 0, stream>>>(actA, aiw_b, BTc, 3*Dc, Dc, ep);
    // attention -> ao (reuses actA)
    attn_kernel<<<2048, 256, 0, stream>>>(qbuf, kbuf, vbuf, actA);
    // x2 = x1 + ao@aow^T + aob (in place)
    ep = EpiParams{}; ep.bias = attn_out_b; ep.fin = xres; ep.fout = xres;
    gemm_tiled<2><<<(BTc/BM)*(Dc/BN), 256, 0, stream>>>(actA, aow_b, BTc, Dc, Dc, ep);
    // LN2
    ln_kernel<<<BTc, 256, 0, stream>>>(xres, norm2_g, norm2_b, actA);
    // mlp1 (silu) -> mbuf
    ep = EpiParams{}; ep.bias = mlp_b1; ep.bout = mbuf;
    gemm_tiled<1><<<(BTc/BM)*(MLPc/BN), 256, 0, stream>>>(actA, w1_b, BTc, MLPc, Dc, ep);
    // mlp2 + residual -> final x
    ep = EpiParams{}; ep.bias = mlp_b2; ep.fin = xres; ep.fout = out_x;
    gemm_tiled<2><<<(BTc/BM)*(Dc/BN), 256, 0, stream>>>(mbuf, w2_b, BTc, Dc, MLPc, ep);

    (void)in_sizes; (void)n_in; (void)out_size; (void)ws_size;
}

// Round 3
// 695.055 us; speedup vs baseline: 2.7023x; 1.1503x over previous
//
#include <hip/hip_runtime.h>

// ---------------------------------------------------------------------------
// TENProLayer on MI355X — round 2: MFMA flash attention + transposed-V qkv.
// ---------------------------------------------------------------------------

typedef __bf16 bf16_t;
typedef bf16_t bf16x8 __attribute__((ext_vector_type(8)));
typedef bf16_t bf16x4 __attribute__((ext_vector_type(4)));
typedef float  f32x4  __attribute__((ext_vector_type(4)));

#define Tc   2048
#define Dc   1024
#define BTc  8192     // B*T
#define K2c  128      // 2K
#define MLPc 4096

// ---------------------------------------------------------------------------
// fp32 -> bf16 conversion (9 segments in one launch)
// ---------------------------------------------------------------------------
struct ConvSeg { const float* src; bf16_t* dst; int n; };
struct ConvArgs { ConvSeg s[9]; };

__global__ __launch_bounds__(256) void convert_kernel(ConvArgs a) {
    ConvSeg sg = a.s[blockIdx.y];
    int i = (blockIdx.x * 256 + threadIdx.x) * 4;
    if (i >= sg.n) return;
    float4 v = *(const float4*)(sg.src + i);
    bf16x4 o;
    o[0] = (bf16_t)v.x; o[1] = (bf16_t)v.y; o[2] = (bf16_t)v.z; o[3] = (bf16_t)v.w;
    *(bf16x4*)(sg.dst + i) = o;
}

// ---------------------------------------------------------------------------
// LayerNorm: fp32 in -> bf16 out. One block per row (D=1024).
// ---------------------------------------------------------------------------
__global__ __launch_bounds__(256) void ln_kernel(const float* __restrict__ x,
                                                 const float* __restrict__ g,
                                                 const float* __restrict__ bb,
                                                 bf16_t* __restrict__ out) {
    int row = blockIdx.x;
    int tid = threadIdx.x;
    float4 v = ((const float4*)(x + (size_t)row * Dc))[tid];
    float s  = v.x + v.y + v.z + v.w;
    float ss = v.x * v.x + v.y * v.y + v.z * v.z + v.w * v.w;
#pragma unroll
    for (int d = 32; d > 0; d >>= 1) {
        s  += __shfl_down(s, d);
        ss += __shfl_down(ss, d);
    }
    __shared__ float red[8];
    int wv = tid >> 6;
    if ((tid & 63) == 0) { red[wv] = s; red[4 + wv] = ss; }
    __syncthreads();
    s  = red[0] + red[1] + red[2] + red[3];
    ss = red[4] + red[5] + red[6] + red[7];
    float mean = s * (1.0f / Dc);
    float var  = ss * (1.0f / Dc) - mean * mean;
    float rstd = rsqrtf(var + 1e-5f);
    float4 g4 = ((const float4*)g)[tid];
    float4 b4 = ((const float4*)bb)[tid];
    bf16x4 o;
    o[0] = (bf16_t)((v.x - mean) * rstd * g4.x + b4.x);
    o[1] = (bf16_t)((v.y - mean) * rstd * g4.y + b4.y);
    o[2] = (bf16_t)((v.z - mean) * rstd * g4.z + b4.z);
    o[3] = (bf16_t)((v.w - mean) * rstd * g4.w + b4.w);
    *(bf16x4*)(out + (size_t)row * Dc + tid * 4) = o;
}

// ---------------------------------------------------------------------------
// m97-style tiled GEMM: C[m,n] = sum_k A[m,k]*W[n,k] (both row-major bf16).
// 128x128 tile, BK=32, 4 waves x (64x64), global_load_lds width-16 staging.
// ---------------------------------------------------------------------------
#define BM 128
#define BN 128
#define BK 32

struct EpiParams {
    const float* bias;
    float*       fout;
    const float* fin;
    bf16_t*      bout;
    bf16_t*      q; bf16_t* k; bf16_t* v;
    const float* hbuf;
};

#define GLOAD_LDS(g, l)                                                        \
    __builtin_amdgcn_global_load_lds(                                          \
        (const __attribute__((address_space(1))) unsigned int*)(g),            \
        (__attribute__((address_space(3))) unsigned int*)(l), 16, 0, 0)

template <int EPI>
__global__ __launch_bounds__(256) void gemm_tiled(const bf16_t* __restrict__ A,
                                                  const bf16_t* __restrict__ W,
                                                  int M, int N, int K,
                                                  EpiParams ep) {
    __shared__ bf16_t As[BM * BK];
    __shared__ bf16_t Bs[BN * BK];

    int tid = threadIdx.x;
    int wv = tid >> 6, lane = tid & 63;
    int lane16 = lane & 15, quad = lane >> 4;
    int nbn = N / BN;
    int bm = blockIdx.x / nbn, bn = blockIdx.x % nbn;
    int m0 = bm * BM, n0 = bn * BN;
    int wm = (wv >> 1) * 64, wn = (wv & 1) * 64;

    int lrow = lane >> 2;
    int lcol = (lane & 3) * 8;
    const bf16_t* ga = A + (size_t)(m0 + wv * 16 + lrow) * K + lcol;
    const bf16_t* gb = W + (size_t)(n0 + wv * 16 + lrow) * K + lcol;
    size_t gstep64 = (size_t)64 * K;
    bf16_t* la0 = &As[(wv * 16) * BK];
    bf16_t* la1 = &As[(64 + wv * 16) * BK];
    bf16_t* lb0 = &Bs[(wv * 16) * BK];
    bf16_t* lb1 = &Bs[(64 + wv * 16) * BK];

    f32x4 zz = {0.f, 0.f, 0.f, 0.f};
    f32x4 acc[4][4];
#pragma unroll
    for (int mi = 0; mi < 4; mi++)
#pragma unroll
        for (int ni = 0; ni < 4; ni++) acc[mi][ni] = zz;

    for (int k0 = 0; k0 < K; k0 += BK) {
        GLOAD_LDS(ga + k0, la0);
        GLOAD_LDS(ga + k0 + gstep64, la1);
        GLOAD_LDS(gb + k0, lb0);
        GLOAD_LDS(gb + k0 + gstep64, lb1);
        __syncthreads();
        bf16x8 af[4], bfr[4];
#pragma unroll
        for (int mi = 0; mi < 4; mi++)
            af[mi] = *(const bf16x8*)&As[(wm + mi * 16 + lane16) * BK + quad * 8];
#pragma unroll
        for (int ni = 0; ni < 4; ni++)
            bfr[ni] = *(const bf16x8*)&Bs[(wn + ni * 16 + lane16) * BK + quad * 8];
#pragma unroll
        for (int mi = 0; mi < 4; mi++)
#pragma unroll
            for (int ni = 0; ni < 4; ni++)
                acc[mi][ni] = __builtin_amdgcn_mfma_f32_16x16x32_bf16(
                    af[mi], bfr[ni], acc[mi][ni], 0, 0, 0);
        __syncthreads();
    }

#pragma unroll
    for (int mi = 0; mi < 4; mi++)
#pragma unroll
        for (int ni = 0; ni < 4; ni++)
#pragma unroll
            for (int r = 0; r < 4; r++) {
                int row = m0 + wm + mi * 16 + quad * 4 + r;
                int col = n0 + wn + ni * 16 + lane16;
                float v = acc[mi][ni][r];
                if constexpr (EPI == 0) {          // plain fp32 store
                    ep.fout[(size_t)row * N + col] = v;
                } else if constexpr (EPI == 1) {   // mlp1: silu -> bf16
                    v += ep.bias[col];
                    ep.bout[(size_t)row * N + col] = (bf16_t)(v / (1.0f + __expf(-v)));
                } else if constexpr (EPI == 2) {   // residual + bias -> fp32
                    size_t o = (size_t)row * N + col;
                    ep.fout[o] = ep.fin[o] + v + ep.bias[col];
                } else if constexpr (EPI == 3) {   // q/k: bias + scatter bf16
                    v += ep.bias[col];
                    int part = col >> 10, d1 = col & 1023;
                    int hh = d1 >> 8, hd = d1 & 255;
                    int b = row >> 11, t = row & 2047;
                    bf16_t* dst = (part == 0) ? ep.q : ep.k;
                    dst[(((size_t)(b * 4 + hh) * Tc + t) << 8) + hd] = (bf16_t)v;
                } else if constexpr (EPI == 4) {   // spectral gate
                    size_t o = (size_t)row * N + col;
                    float g = 1.0f / (1.0f + __expf(-(v + ep.bias[col])));
                    ep.fout[o] = ep.fin[o] + g * ep.hbuf[o];
                } else if constexpr (EPI == 5) {   // V^T: row=dim, col=bt
                    v += ep.bias[2048 + row];
                    int b = col >> 11, t = col & 2047;
                    int hh = row >> 8, dd = row & 255;
                    ep.v[((size_t)((b * 4 + hh) * 256 + dd)) * Tc + t] = (bf16_t)v;
                }
            }
}

// ---------------------------------------------------------------------------
// Small-N GEMM (beta, N=128): 32x32-per-wave direct-load MFMA.
// ---------------------------------------------------------------------------
__device__ __forceinline__ void mm32(const bf16_t* __restrict__ A,
                                     const bf16_t* __restrict__ W,
                                     int K, int m0, int n0,
                                     int lane16, int quad, f32x4 (&acc)[2][2]) {
    const bf16_t* a0 = A + (size_t)(m0 + lane16) * K + quad * 8;
    const bf16_t* a1 = a0 + (size_t)16 * K;
    const bf16_t* w0 = W + (size_t)(n0 + lane16) * K + quad * 8;
    const bf16_t* w1 = w0 + (size_t)16 * K;
#pragma unroll 4
    for (int k = 0; k < K; k += 32) {
        bf16x8 av0 = *(const bf16x8*)(a0 + k);
        bf16x8 av1 = *(const bf16x8*)(a1 + k);
        bf16x8 bv0 = *(const bf16x8*)(w0 + k);
        bf16x8 bv1 = *(const bf16x8*)(w1 + k);
        acc[0][0] = __builtin_amdgcn_mfma_f32_16x16x32_bf16(av0, bv0, acc[0][0], 0, 0, 0);
        acc[0][1] = __builtin_amdgcn_mfma_f32_16x16x32_bf16(av0, bv1, acc[0][1], 0, 0, 0);
        acc[1][0] = __builtin_amdgcn_mfma_f32_16x16x32_bf16(av1, bv0, acc[1][0], 0, 0, 0);
        acc[1][1] = __builtin_amdgcn_mfma_f32_16x16x32_bf16(av1, bv1, acc[1][1], 0, 0, 0);
    }
}

__global__ __launch_bounds__(256) void gemm_beta(const bf16_t* __restrict__ xn,
                                                 const bf16_t* __restrict__ ipw,
                                                 const bf16_t* __restrict__ prevb,
                                                 const bf16_t* __restrict__ mpw,
                                                 const float* __restrict__ mgate_p,
                                                 float* __restrict__ beta_c) {
    int lane = threadIdx.x & 63;
    int wave = threadIdx.x >> 6;
    int gid  = blockIdx.x * 4 + wave;
    int mt = gid / 4, nt = gid % 4;
    int m0 = mt * 32, n0 = nt * 32;
    int lane16 = lane & 15, quad = lane >> 4;
    f32x4 zz = {0.f, 0.f, 0.f, 0.f};
    f32x4 acc[2][2] = {{zz, zz}, {zz, zz}};
    mm32(xn, ipw, Dc, m0, n0, lane16, quad, acc);
    f32x4 acc2[2][2] = {{zz, zz}, {zz, zz}};
    mm32(prevb, mpw, K2c, m0, n0, lane16, quad, acc2);
    float mg = 1.0f / (1.0f + __expf(-mgate_p[0]));
    for (int mi = 0; mi < 2; mi++)
        for (int ni = 0; ni < 2; ni++)
            for (int r = 0; r < 4; r++) {
                int row = m0 + mi * 16 + quad * 4 + r;
                int col = n0 + ni * 16 + lane16;
                int b = row >> 11, t = row & 2047;
                beta_c[((size_t)b * K2c + col) * Tc + t] =
                    acc[mi][ni][r] + mg * acc2[mi][ni][r];
            }
}

// ---------------------------------------------------------------------------
// Complex diagonal SSM scan (wave-parallel Kogge-Stone, 32 steps/lane).
// ---------------------------------------------------------------------------
__global__ __launch_bounds__(64) void scan_kernel(const float* __restrict__ beta_c,
                                                  const float* __restrict__ log_decay,
                                                  const float* __restrict__ freq,
                                                  float* __restrict__ cbuf) {
    int b = blockIdx.x >> 6;
    int k = blockIdx.x & 63;
    int lane = threadIdx.x;
    float lam = expf(log_decay[k]);
    float fr = freq[k];
    float lr = lam * cosf(fr), li = lam * sinf(fr);

    const float* br_p = beta_c + ((size_t)b * K2c + k) * Tc + lane * 32;
    const float* bi_p = beta_c + ((size_t)b * K2c + 64 + k) * Tc + lane * 32;
    float br[32], bi[32];
#pragma unroll
    for (int i = 0; i < 8; i++) {
        *(float4*)(&br[i * 4]) = ((const float4*)br_p)[i];
        *(float4*)(&bi[i * 4]) = ((const float4*)bi_p)[i];
    }
    float sr = 0.f, si = 0.f;
#pragma unroll
    for (int i = 0; i < 32; i++) {
        float nr = lr * sr - li * si + br[i];
        float ni = lr * si + li * sr + bi[i];
        sr = nr; si = ni;
    }
    float Mr = lr, Mi = li;
#pragma unroll
    for (int i = 0; i < 5; i++) {
        float nr = Mr * Mr - Mi * Mi, ni = 2.f * Mr * Mi;
        Mr = nr; Mi = ni;
    }
    float ir = sr, ii = si;
#pragma unroll
    for (int d = 1; d < 64; d <<= 1) {
        float pr = __shfl_up(ir, d);
        float pi = __shfl_up(ii, d);
        if (lane >= d) {
            ir += Mr * pr - Mi * pi;
            ii += Mr * pi + Mi * pr;
        }
        float nr = Mr * Mr - Mi * Mi, ni = 2.f * Mr * Mi;
        Mr = nr; Mi = ni;
    }
    float cr = __shfl_up(ir, 1), ci = __shfl_up(ii, 1);
    if (lane == 0) { cr = 0.f; ci = 0.f; }
    float* cr_p = cbuf + ((size_t)b * K2c + k) * Tc + lane * 32;
    float* ci_p = cbuf + ((size_t)b * K2c + 64 + k) * Tc + lane * 32;
    sr = cr; si = ci;
#pragma unroll
    for (int i = 0; i < 32; i++) {
        float nr = lr * sr - li * si + br[i];
        float ni = lr * si + li * sr + bi[i];
        sr = nr; si = ni;
        cr_p[i] = sr; ci_p[i] = si;
    }
}

// ---------------------------------------------------------------------------
// Per-head coupling + concat -> eigenstates (fp32 output #2 + bf16 copy)
// ---------------------------------------------------------------------------
__global__ __launch_bounds__(256) void coupling_kernel(const float* __restrict__ cbuf,
                                                       const float* __restrict__ cpl,
                                                       float* __restrict__ eig_out,
                                                       bf16_t* __restrict__ eigb) {
    int idx = blockIdx.x * 256 + threadIdx.x;
    int col = idx & 127;
    int t = (idx >> 7) & 2047;
    int b = idx >> 18;
    int ri = col >> 6, hj = col & 63, h2 = hj >> 4, j = hj & 15;
    const float* crow = cbuf + ((size_t)b * K2c + ri * 64 + h2 * 16) * Tc + t;
    const float* cw = cpl + (h2 * 16 + j) * 16;
    float acc = 0.f;
#pragma unroll
    for (int kk = 0; kk < 16; kk++) acc += cw[kk] * crow[(size_t)kk * Tc];
    eig_out[idx] = acc;
    eigb[idx] = (bf16_t)acc;
}

// ---------------------------------------------------------------------------
// MFMA sliding-window attention. Wave = 16 queries, key span 144 (9 tiles).
// Q: (bh,t,256); K: (bh,t,256); V^T: (bh,256,t). P via per-wave LDS.
// ---------------------------------------------------------------------------
#define LDP 168   // padded P row stride (bf16): 84 dwords, odd*4 -> conflict-light

__global__ __launch_bounds__(256) void attn_mfma(const bf16_t* __restrict__ qb,
                                                 const bf16_t* __restrict__ kb,
                                                 const bf16_t* __restrict__ vt,
                                                 bf16_t* __restrict__ ao) {
    __shared__ bf16_t Pl[4 * 16 * LDP];
    int tid = threadIdx.x;
    int wv = tid >> 6, lane = tid & 63;
    int lane16 = lane & 15, quad = lane >> 4;
    int qblk = blockIdx.x & 31;
    int bh = blockIdx.x >> 5;
    int qw0 = qblk * 64 + wv * 16;
    const bf16_t* qp = qb + (size_t)bh * Tc * 256;
    const bf16_t* kp = kb + (size_t)bh * Tc * 256;
    const bf16_t* vp = vt + (size_t)bh * 256 * Tc;
    bf16_t* Pw = &Pl[wv * 16 * LDP];

    // zero the pad region (cols 144..167); cols 0..143 are fully overwritten
    for (int i = lane; i < 16 * 24; i += 64) {
        int r = i / 24, c = 144 + (i % 24);
        Pw[r * LDP + c] = (bf16_t)0.f;
    }

    // preload Q fragments (A-operand): row=lane16, k=ks*32+quad*8
    bf16x8 qf[8];
#pragma unroll
    for (int ks = 0; ks < 8; ks++)
        qf[ks] = *(const bf16x8*)(qp + (size_t)(qw0 + lane16) * 256 + ks * 32 + quad * 8);

    f32x4 zz = {0.f, 0.f, 0.f, 0.f};
    f32x4 S[9];
#pragma unroll
    for (int jt = 0; jt < 9; jt++) S[jt] = zz;
    int kbase = qw0 - 128;

    // ---- S = Q K^T ----
#pragma unroll
    for (int ks = 0; ks < 8; ks++) {
        bf16x8 kf[9];
#pragma unroll
        for (int jt = 0; jt < 9; jt++) {
            int krow = kbase + jt * 16 + lane16;
            krow = krow < 0 ? 0 : krow;
            kf[jt] = *(const bf16x8*)(kp + (size_t)krow * 256 + ks * 32 + quad * 8);
        }
#pragma unroll
        for (int jt = 0; jt < 9; jt++)
            S[jt] = __builtin_amdgcn_mfma_f32_16x16x32_bf16(qf[ks], kf[jt], S[jt], 0, 0, 0);
    }

    // ---- mask + scale + softmax (rows = qw0 + quad*4 + r) ----
    float m[4], l[4];
#pragma unroll
    for (int r = 0; r < 4; r++) m[r] = -1e30f;
#pragma unroll
    for (int jt = 0; jt < 9; jt++) {
        int kg = kbase + jt * 16 + lane16;
#pragma unroll
        for (int r = 0; r < 4; r++) {
            int qrow = qw0 + quad * 4 + r;
            bool ok = (kg >= 0) && (kg <= qrow) && (kg >= qrow - 128);
            float v = ok ? S[jt][r] * 0.0625f : -1e30f;
            S[jt][r] = v;
            m[r] = fmaxf(m[r], v);
        }
    }
#pragma unroll
    for (int d = 1; d < 16; d <<= 1)
#pragma unroll
        for (int r = 0; r < 4; r++)
            m[r] = fmaxf(m[r], __shfl_xor(m[r], d));
#pragma unroll
    for (int r = 0; r < 4; r++) l[r] = 0.f;
#pragma unroll
    for (int jt = 0; jt < 9; jt++)
#pragma unroll
        for (int r = 0; r < 4; r++) {
            float p = __expf(S[jt][r] - m[r]);
            S[jt][r] = p;
            l[r] += p;
        }
#pragma unroll
    for (int d = 1; d < 16; d <<= 1)
#pragma unroll
        for (int r = 0; r < 4; r++)
            l[r] += __shfl_xor(l[r], d);

    // ---- P -> LDS (row=query, col=key), bf16 ----
#pragma unroll
    for (int jt = 0; jt < 9; jt++)
#pragma unroll
        for (int r = 0; r < 4; r++)
            Pw[(quad * 4 + r) * LDP + jt * 16 + lane16] = (bf16_t)S[jt][r];
    __syncthreads();

    // ---- O = P V  (A from LDS P; B = V^T rows) ----
    f32x4 O[16];
#pragma unroll
    for (int nt = 0; nt < 16; nt++) O[nt] = zz;
#pragma unroll
    for (int ks = 0; ks < 5; ks++) {
        bf16x8 pf = *(const bf16x8*)&Pw[lane16 * LDP + ks * 32 + quad * 8];
        int kidx = kbase + ks * 32 + quad * 8;
        kidx = kidx < 0 ? 0 : kidx;
        kidx = kidx > (Tc - 8) ? (Tc - 8) : kidx;
#pragma unroll
        for (int nt = 0; nt < 16; nt++) {
            bf16x8 vf = *(const bf16x8*)(vp + (size_t)(nt * 16 + lane16) * Tc + kidx);
            O[nt] = __builtin_amdgcn_mfma_f32_16x16x32_bf16(pf, vf, O[nt], 0, 0, 0);
        }
    }

    float rl[4];
#pragma unroll
    for (int r = 0; r < 4; r++) rl[r] = 1.0f / l[r];
    int b = bh >> 2, h = bh & 3;
#pragma unroll
    for (int nt = 0; nt < 16; nt++)
#pragma unroll
        for (int r = 0; r < 4; r++) {
            int qrow = qw0 + quad * 4 + r;
            int dim = nt * 16 + lane16;
            ao[((size_t)(b * Tc + qrow)) * Dc + h * 256 + dim] = (bf16_t)(O[nt][r] * rl[r]);
        }
}

// ---------------------------------------------------------------------------
// Launch
// ---------------------------------------------------------------------------
extern "C" void kernel_launch(void* const* d_in, const int* in_sizes, int n_in,
                              void* d_out, int out_size, void* d_ws, size_t ws_size,
                              hipStream_t stream) {
    const float* x            = (const float*)d_in[0];
    const float* prev_eig     = (const float*)d_in[1];
    const float* norm1_g      = (const float*)d_in[2];
    const float* norm1_b      = (const float*)d_in[3];
    const float* in_proj_w    = (const float*)d_in[4];
    const float* memory_gate  = (const float*)d_in[5];
    const float* memory_proj_w= (const float*)d_in[6];
    const float* log_decay    = (const float*)d_in[7];
    const float* frequency    = (const float*)d_in[8];
    const float* coupling     = (const float*)d_in[9];
    const float* main_gate_w  = (const float*)d_in[10];
    const float* main_gate_b  = (const float*)d_in[11];
    const float* out_proj_w   = (const float*)d_in[12];
    const float* attn_norm_g  = (const float*)d_in[13];
    const float* attn_norm_b  = (const float*)d_in[14];
    const float* attn_in_w    = (const float*)d_in[15];
    const float* attn_in_b    = (const float*)d_in[16];
    const float* attn_out_w   = (const float*)d_in[17];
    const float* attn_out_b   = (const float*)d_in[18];
    const float* norm2_g      = (const float*)d_in[19];
    const float* norm2_b      = (const float*)d_in[20];
    const float* mlp_w1       = (const float*)d_in[21];
    const float* mlp_b1       = (const float*)d_in[22];
    const float* mlp_w2       = (const float*)d_in[23];
    const float* mlp_b2       = (const float*)d_in[24];

    char* ws = (char*)d_ws;
    bf16_t* ipw_b  = (bf16_t*)(ws + 0);
    bf16_t* mpw_b  = (bf16_t*)(ws + 262144);
    bf16_t* mgw_b  = (bf16_t*)(ws + 294912);
    bf16_t* opw_b  = (bf16_t*)(ws + 2392064);
    bf16_t* aiw_b  = (bf16_t*)(ws + 2654208);
    bf16_t* aow_b  = (bf16_t*)(ws + 8945664);
    bf16_t* w1_b   = (bf16_t*)(ws + 11042816);
    bf16_t* w2_b   = (bf16_t*)(ws + 19431424);
    bf16_t* prev_b = (bf16_t*)(ws + 27820032);
    const size_t OFF_ACTA = 29917184;
    const size_t OFF_BIG  = OFF_ACTA + 16777216;
    bf16_t* actA   = (bf16_t*)(ws + OFF_ACTA);
    float*  beta_c = (float*)(ws + OFF_BIG);
    float*  cbuf   = (float*)(ws + OFF_BIG + 4194304);
    bf16_t* eigb   = (bf16_t*)(ws + OFF_BIG + 8388608);
    float*  hbuf   = (float*)(ws + OFF_BIG + 16777216);        // dead before kbuf
    bf16_t* qbuf   = (bf16_t*)(ws + OFF_BIG);
    bf16_t* kbuf   = (bf16_t*)(ws + OFF_BIG + 16777216);
    bf16_t* vtbuf  = (bf16_t*)(ws + OFF_BIG + 33554432);       // (b,h,d,t)
    bf16_t* mbuf   = (bf16_t*)(ws + OFF_BIG);

    float* out_x   = (float*)d_out;
    float* out_eig = out_x + (size_t)BTc * Dc;
    float* xres    = out_x;

    ConvArgs ca;
    ca.s[0] = ConvSeg{in_proj_w,     ipw_b,  131072};
    ca.s[1] = ConvSeg{memory_proj_w, mpw_b,  16384};
    ca.s[2] = ConvSeg{main_gate_w,   mgw_b,  1048576};
    ca.s[3] = ConvSeg{out_proj_w,    opw_b,  131072};
    ca.s[4] = ConvSeg{attn_in_w,     aiw_b,  3145728};
    ca.s[5] = ConvSeg{attn_out_w,    aow_b,  1048576};
    ca.s[6] = ConvSeg{mlp_w1,        w1_b,   4194304};
    ca.s[7] = ConvSeg{mlp_w2,        w2_b,   4194304};
    ca.s[8] = ConvSeg{prev_eig,      prev_b, 1048576};
    convert_kernel<<<dim3(4096, 9), 256, 0, stream>>>(ca);

    EpiParams ep{};

    ln_kernel<<<BTc, 256, 0, stream>>>(x, norm1_g, norm1_b, actA);
    gemm_beta<<<256, 256, 0, stream>>>(actA, ipw_b, prev_b, mpw_b, memory_gate, beta_c);
    scan_kernel<<<256, 64, 0, stream>>>(beta_c, log_decay, frequency, cbuf);
    coupling_kernel<<<4096, 256, 0, stream>>>(cbuf, coupling, out_eig, eigb);
    // h = eig @ opw^T
    ep = EpiParams{}; ep.fout = hbuf;
    gemm_tiled<0><<<(BTc/BM)*(Dc/BN), 256, 0, stream>>>(eigb, opw_b, BTc, Dc, K2c, ep);
    // x1 = x + sigmoid(xn@mgw^T + mgb) * h
    ep = EpiParams{}; ep.bias = main_gate_b; ep.fin = x; ep.fout = xres; ep.hbuf = hbuf;
    gemm_tiled<4><<<(BTc/BM)*(Dc/BN), 256, 0, stream>>>(actA, mgw_b, BTc, Dc, Dc, ep);
    ln_kernel<<<BTc, 256, 0, stream>>>(xres, attn_norm_g, attn_norm_b, actA);
    // q,k (N=2048)
    ep = EpiParams{}; ep.bias = attn_in_b; ep.q = qbuf; ep.k = kbuf;
    gemm_tiled<3><<<(BTc/BM)*(2048/BN), 256, 0, stream>>>(actA, aiw_b, BTc, 2048, Dc, ep);
    // V^T (M=1024 dims, N=8192 tokens): A = V-weights, W = activations
    ep = EpiParams{}; ep.bias = attn_in_b; ep.v = vtbuf;
    gemm_tiled<5><<<(Dc/BM)*(BTc/BN), 256, 0, stream>>>(aiw_b + (size_t)2048 * Dc, actA,
                                                        Dc, BTc, Dc, ep);
    // attention -> ao (reuses actA)
    attn_mfma<<<512, 256, 0, stream>>>(qbuf, kbuf, vtbuf, actA);
    // x2 = x1 + ao@aow^T + aob
    ep = EpiParams{}; ep.bias = attn_out_b; ep.fin = xres; ep.fout = xres;
    gemm_tiled<2><<<(BTc/BM)*(Dc/BN), 256, 0, stream>>>(actA, aow_b, BTc, Dc, Dc, ep);
    ln_kernel<<<BTc, 256, 0, stream>>>(xres, norm2_g, norm2_b, actA);
    // mlp1 (silu)
    ep = EpiParams{}; ep.bias = mlp_b1; ep.bout = mbuf;
    gemm_tiled<1><<<(BTc/BM)*(MLPc/BN), 256, 0, stream>>>(actA, w1_b, BTc, MLPc, Dc, ep);
    // mlp2 + residual
    ep = EpiParams{}; ep.bias = mlp_b2; ep.fin = xres; ep.fout = out_x;
    gemm_tiled<2><<<(BTc/BM)*(Dc/BN), 256, 0, stream>>>(mbuf, w2_b, BTc, Dc, MLPc, ep);

    (void)in_sizes; (void)n_in; (void)out_size; (void)ws_size;
}